// Round 1
// baseline (445.019 us; speedup 1.0000x reference)
//
#include <hip/hip_runtime.h>

using f32x4  = __attribute__((ext_vector_type(4))) float;
using bf16x8 = __attribute__((ext_vector_type(8))) __bf16;
using u16x4  = __attribute__((ext_vector_type(4))) unsigned short;

#define BM 128
#define BN 128
#define BK 64

__device__ __forceinline__ unsigned short f32_to_bf16_bits(float f) {
    // round-to-nearest-even bf16 (finite inputs only)
    unsigned int u = __builtin_bit_cast(unsigned int, f);
    u = (u + 0x7fffu + ((u >> 16) & 1u)) >> 16;
    return (unsigned short)u;
}

__device__ __forceinline__ void gload_lds16(const void* g, void* l) {
    __builtin_amdgcn_global_load_lds(
        (const __attribute__((address_space(1))) unsigned int*)g,
        (__attribute__((address_space(3))) unsigned int*)l,
        16, 0, 0);
}

// ---------------------------------------------------------------------------
// Fake-quant x: per-group-of-64 (along K) symmetric absmax int8 quant,
// dequantized and stored as bf16. Each lane handles 4 contiguous floats;
// a 64-element group = 16 lanes; absmax reduced via shfl_xor within the
// 16-lane segment. All quant arithmetic is exact-f32 (matches jax ref
// bit-for-bit); only the final bf16 store rounds.
// ---------------------------------------------------------------------------
__global__ void quant_kernel(const float* __restrict__ x,
                             unsigned short* __restrict__ xq,
                             int total4) {
    int idx = blockIdx.x * 256 + threadIdx.x;
    if (idx >= total4) return;
    f32x4 v = *(const f32x4*)(x + (size_t)idx * 4);
    float am = fmaxf(fmaxf(fabsf(v[0]), fabsf(v[1])),
                     fmaxf(fabsf(v[2]), fabsf(v[3])));
    am = fmaxf(am, __shfl_xor(am, 1));
    am = fmaxf(am, __shfl_xor(am, 2));
    am = fmaxf(am, __shfl_xor(am, 4));
    am = fmaxf(am, __shfl_xor(am, 8));
    // delta = max(2*absmax/254, 1e-5) == max(absmax/127, 1e-5) exactly in f32
    float delta = fmaxf(am / 127.0f, 1e-5f);
    u16x4 o;
#pragma unroll
    for (int i = 0; i < 4; ++i) {
        float q = rintf(v[i] / delta);           // rintf = round-half-even
        q = fminf(fmaxf(q, -127.0f), 127.0f);
        o[i] = f32_to_bf16_bits(q * delta);
    }
    *(u16x4*)(xq + (size_t)idx * 4) = o;
}

// W f32 -> bf16 bits
__global__ void wconv_kernel(const float* __restrict__ W,
                             unsigned short* __restrict__ Wb,
                             int total4) {
    int idx = blockIdx.x * 256 + threadIdx.x;
    if (idx >= total4) return;
    f32x4 v = *(const f32x4*)(W + (size_t)idx * 4);
    u16x4 o;
#pragma unroll
    for (int i = 0; i < 4; ++i) o[i] = f32_to_bf16_bits(v[i]);
    *(u16x4*)(Wb + (size_t)idx * 4) = o;
}

// ---------------------------------------------------------------------------
// bf16 GEMM, B^T layout: out[m][n] = sum_k A[m][k]*B[n][k] + bias[n].
// m97 structure: 128x128 tile, BK=64, 4 waves (2x2), each wave 64x64 out
// (4x4 frags of 16x16x32 MFMA), global_load_lds width-16 staging, 2-barrier
// K loop. A tile [128][64] bf16 (16KB) + B tile (16KB) single-buffered LDS.
// ---------------------------------------------------------------------------
__global__ __launch_bounds__(256) void gemm_kernel(
    const unsigned short* __restrict__ A,   // [M][K] bf16 bits (quantized x)
    const unsigned short* __restrict__ B,   // [N][K] bf16 bits (W, B^T layout)
    const float* __restrict__ bias,         // [N]
    float* __restrict__ out,                // [M][N] f32
    int M, int N, int K)
{
    __shared__ unsigned short As[BM * BK];  // [row][k] linear
    __shared__ unsigned short Bs[BN * BK];

    const int tid  = threadIdx.x;
    const int wv   = tid >> 6;      // wave 0..3
    const int lane = tid & 63;

    const int nbn = N / BN;
    const int nwg = gridDim.x;
    // bijective XCD swizzle (nwg % 8 == 0 here: 2048)
    const int cpx = nwg >> 3;
    const int swz = (blockIdx.x & 7) * cpx + (blockIdx.x >> 3);
    const int bm0 = (swz / nbn) * BM;
    const int bn0 = (swz % nbn) * BN;

    const int wm = wv >> 1;         // wave row 0..1
    const int wn = wv & 1;          // wave col 0..1
    const int lr = lane & 15;       // fragment row (A) / col (C)
    const int lk = (lane >> 4) << 3;// k-offset within 32-chunk

    f32x4 acc[4][4] = {};

    for (int k0 = 0; k0 < K; k0 += BK) {
        // stage A and B tiles: 4 issues each, 16B/lane
#pragma unroll
        for (int i = 0; i < 4; ++i) {
            int u   = i * 256 + tid;        // 16B-unit index in tile
            int row = u >> 3;               // 8 units (128B) per row
            int col = (u & 7) << 3;         // ushort column
            int ldsu = (i * 256 + wv * 64) * 8; // wave-uniform LDS base (ushorts)
            gload_lds16(A + (size_t)(bm0 + row) * K + k0 + col, As + ldsu);
            gload_lds16(B + (size_t)(bn0 + row) * K + k0 + col, Bs + ldsu);
        }
        __syncthreads();   // drains vmcnt before barrier (compiler-inserted)

#pragma unroll
        for (int kk = 0; kk < 2; ++kk) {
            bf16x8 af[4], bfr[4];
#pragma unroll
            for (int m = 0; m < 4; ++m)
                af[m] = *(const bf16x8*)&As[(wm * 64 + m * 16 + lr) * BK + kk * 32 + lk];
#pragma unroll
            for (int n = 0; n < 4; ++n)
                bfr[n] = *(const bf16x8*)&Bs[(wn * 64 + n * 16 + lr) * BK + kk * 32 + lk];
#pragma unroll
            for (int m = 0; m < 4; ++m)
#pragma unroll
                for (int n = 0; n < 4; ++n)
                    acc[m][n] = __builtin_amdgcn_mfma_f32_16x16x32_bf16(
                        af[m], bfr[n], acc[m][n], 0, 0, 0);
        }
        __syncthreads();
    }

    // epilogue: C/D layout col = lane&15, row = (lane>>4)*4 + j  [m89]
    const int r0   = bm0 + wm * 64;
    const int c0   = bn0 + wn * 64;
    const int rsub = (lane >> 4) << 2;
#pragma unroll
    for (int n = 0; n < 4; ++n) {
        int col = c0 + n * 16 + lr;
        float bv = bias[col];
#pragma unroll
        for (int m = 0; m < 4; ++m) {
            int row = r0 + m * 16 + rsub;
#pragma unroll
            for (int j = 0; j < 4; ++j)
                out[(size_t)(row + j) * N + col] = acc[m][n][j] + bv;
        }
    }
}

extern "C" void kernel_launch(void* const* d_in, const int* in_sizes, int n_in,
                              void* d_out, int out_size, void* d_ws, size_t ws_size,
                              hipStream_t stream) {
    const float* x = (const float*)d_in[0];   // [M][K] f32
    const float* W = (const float*)d_in[1];   // [N][K] f32
    const float* b = (const float*)d_in[2];   // [N]   f32
    float* out = (float*)d_out;               // [M][N] f32

    const int N = in_sizes[2];                // 4096
    const int K = in_sizes[1] / N;            // 4096
    const int M = in_sizes[0] / K;            // 8192

    // workspace: xq bf16 (M*K*2 = 64MB) + Wb bf16 (N*K*2 = 32MB)
    unsigned short* xq = (unsigned short*)d_ws;
    unsigned short* Wb = xq + (size_t)M * K;

    const int t4x = (int)(((long long)M * K) / 4);
    quant_kernel<<<(t4x + 255) / 256, 256, 0, stream>>>(x, xq, t4x);
    const int t4w = (int)(((long long)N * K) / 4);
    wconv_kernel<<<(t4w + 255) / 256, 256, 0, stream>>>(W, Wb, t4w);

    dim3 grid((M / BM) * (N / BN));
    gemm_kernel<<<grid, 256, 0, stream>>>(xq, Wb, b, out, M, N, K);
}

// Round 2
// 387.194 us; speedup vs baseline: 1.1493x; 1.1493x over previous
//
#include <hip/hip_runtime.h>

using f32x4  = __attribute__((ext_vector_type(4))) float;
using bf16x8 = __attribute__((ext_vector_type(8))) __bf16;
using u16x4  = __attribute__((ext_vector_type(4))) unsigned short;

#define BM 128
#define BN 128
#define BK 64

__device__ __forceinline__ unsigned short f32_to_bf16_bits(float f) {
    // round-to-nearest-even bf16 (finite inputs only)
    unsigned int u = __builtin_bit_cast(unsigned int, f);
    u = (u + 0x7fffu + ((u >> 16) & 1u)) >> 16;
    return (unsigned short)u;
}

__device__ __forceinline__ void gload_lds16(const void* g, void* l) {
    __builtin_amdgcn_global_load_lds(
        (const __attribute__((address_space(1))) unsigned int*)g,
        (__attribute__((address_space(3))) unsigned int*)l,
        16, 0, 0);
}

// ---------------------------------------------------------------------------
// Fake-quant x: per-group-of-64 (along K) symmetric absmax int8 quant,
// dequantized and stored as bf16. Exact-f32 quant math (matches jax ref);
// only the final bf16 store rounds.
// ---------------------------------------------------------------------------
__global__ void quant_kernel(const float* __restrict__ x,
                             unsigned short* __restrict__ xq,
                             int total4) {
    int idx = blockIdx.x * 256 + threadIdx.x;
    if (idx >= total4) return;
    f32x4 v = *(const f32x4*)(x + (size_t)idx * 4);
    float am = fmaxf(fmaxf(fabsf(v[0]), fabsf(v[1])),
                     fmaxf(fabsf(v[2]), fabsf(v[3])));
    am = fmaxf(am, __shfl_xor(am, 1));
    am = fmaxf(am, __shfl_xor(am, 2));
    am = fmaxf(am, __shfl_xor(am, 4));
    am = fmaxf(am, __shfl_xor(am, 8));
    float delta = fmaxf(am / 127.0f, 1e-5f);
    u16x4 o;
#pragma unroll
    for (int i = 0; i < 4; ++i) {
        float q = rintf(v[i] / delta);           // round-half-even
        q = fminf(fmaxf(q, -127.0f), 127.0f);
        o[i] = f32_to_bf16_bits(q * delta);
    }
    *(u16x4*)(xq + (size_t)idx * 4) = o;
}

// W f32 -> bf16 bits
__global__ void wconv_kernel(const float* __restrict__ W,
                             unsigned short* __restrict__ Wb,
                             int total4) {
    int idx = blockIdx.x * 256 + threadIdx.x;
    if (idx >= total4) return;
    f32x4 v = *(const f32x4*)(W + (size_t)idx * 4);
    u16x4 o;
#pragma unroll
    for (int i = 0; i < 4; ++i) o[i] = f32_to_bf16_bits(v[i]);
    *(u16x4*)(Wb + (size_t)idx * 4) = o;
}

// ---------------------------------------------------------------------------
// bf16 GEMM, B^T layout: out[m][n] = sum_k A[m][k]*B[n][k] + bias[n].
// 128x128 tile, BK=64, 4 waves (2x2), global_load_lds width-16 staging.
// T2 LDS swizzle (both-sides, rule #21): 16B granule p within a 128B row
// holds logical column granule p^(row&7). Staging keeps LDS dest LINEAR
// (global_load_lds requirement) and pre-swizzles the per-lane GLOBAL source;
// ds_read applies the same XOR. Quarter-wave's 16 lanes then cover all 32
// banks (2-way aliasing = free) instead of a 16-way conflict.
// ---------------------------------------------------------------------------
__global__ __launch_bounds__(256) void gemm_kernel(
    const unsigned short* __restrict__ A,   // [M][K] bf16 bits (quantized x)
    const unsigned short* __restrict__ B,   // [N][K] bf16 bits (W, B^T layout)
    const float* __restrict__ bias,         // [N]
    float* __restrict__ out,                // [M][N] f32
    int M, int N, int K)
{
    __shared__ unsigned short As[BM * BK];
    __shared__ unsigned short Bs[BN * BK];

    const int tid  = threadIdx.x;
    const int wv   = tid >> 6;      // wave 0..3
    const int lane = tid & 63;

    const int nbn = N / BN;
    const int nwg = gridDim.x;
    const int cpx = nwg >> 3;       // bijective XCD swizzle (nwg%8==0: 2048)
    const int swz = (blockIdx.x & 7) * cpx + (blockIdx.x >> 3);
    const int bm0 = (swz / nbn) * BM;
    const int bn0 = (swz % nbn) * BN;

    const int wm = wv >> 1;
    const int wn = wv & 1;
    const int lr = lane & 15;       // fragment row (A/B) / col (C)
    const int sx = lr & 7;          // per-lane row-swizzle key (row&7 == lr&7)

    f32x4 acc[4][4] = {};

    for (int k0 = 0; k0 < K; k0 += BK) {
        // stage A and B tiles: LDS dest linear, global source inverse-swizzled
#pragma unroll
        for (int i = 0; i < 4; ++i) {
            int u    = i * 256 + tid;          // physical 16B-granule index
            int row  = u >> 3;                 // 8 granules (128B) per row
            int c    = (u & 7) ^ (row & 7);    // logical column granule
            int ldsu = (i * 256 + wv * 64) * 8;// wave-uniform LDS base (ushorts)
            gload_lds16(A + (size_t)(bm0 + row) * K + k0 + c * 8, As + ldsu);
            gload_lds16(B + (size_t)(bn0 + row) * K + k0 + c * 8, Bs + ldsu);
        }
        __syncthreads();

#pragma unroll
        for (int kk = 0; kk < 2; ++kk) {
            // swizzled column offset (ushorts) for this lane & k-half
            const int co = (((kk * 4) + (lane >> 4)) ^ sx) << 3;
            bf16x8 af[4], bfr[4];
#pragma unroll
            for (int m = 0; m < 4; ++m)
                af[m] = *(const bf16x8*)&As[(wm * 64 + m * 16 + lr) * BK + co];
#pragma unroll
            for (int n = 0; n < 4; ++n)
                bfr[n] = *(const bf16x8*)&Bs[(wn * 64 + n * 16 + lr) * BK + co];
#pragma unroll
            for (int m = 0; m < 4; ++m)
#pragma unroll
                for (int n = 0; n < 4; ++n)
                    acc[m][n] = __builtin_amdgcn_mfma_f32_16x16x32_bf16(
                        af[m], bfr[n], acc[m][n], 0, 0, 0);
        }
        __syncthreads();
    }

    // epilogue: C/D layout col = lane&15, row = (lane>>4)*4 + j  [m89]
    const int r0   = bm0 + wm * 64;
    const int c0   = bn0 + wn * 64;
    const int rsub = (lane >> 4) << 2;
#pragma unroll
    for (int n = 0; n < 4; ++n) {
        int col = c0 + n * 16 + lr;
        float bv = bias[col];
#pragma unroll
        for (int m = 0; m < 4; ++m) {
            int row = r0 + m * 16 + rsub;
#pragma unroll
            for (int j = 0; j < 4; ++j)
                out[(size_t)(row + j) * N + col] = acc[m][n][j] + bv;
        }
    }
}

extern "C" void kernel_launch(void* const* d_in, const int* in_sizes, int n_in,
                              void* d_out, int out_size, void* d_ws, size_t ws_size,
                              hipStream_t stream) {
    const float* x = (const float*)d_in[0];   // [M][K] f32
    const float* W = (const float*)d_in[1];   // [N][K] f32
    const float* b = (const float*)d_in[2];   // [N]   f32
    float* out = (float*)d_out;               // [M][N] f32

    const int N = in_sizes[2];                // 4096
    const int K = in_sizes[1] / N;            // 4096
    const int M = in_sizes[0] / K;            // 8192

    unsigned short* xq = (unsigned short*)d_ws;            // 64 MB
    unsigned short* Wb = xq + (size_t)M * K;               // 32 MB

    const int t4x = (int)(((long long)M * K) / 4);
    quant_kernel<<<(t4x + 255) / 256, 256, 0, stream>>>(x, xq, t4x);
    const int t4w = (int)(((long long)N * K) / 4);
    wconv_kernel<<<(t4w + 255) / 256, 256, 0, stream>>>(W, Wb, t4w);

    dim3 grid((M / BM) * (N / BN));
    gemm_kernel<<<grid, 256, 0, stream>>>(xq, Wb, b, out, M, N, K);
}

// Round 3
// 307.555 us; speedup vs baseline: 1.4470x; 1.2589x over previous
//
#include <hip/hip_runtime.h>

using f32x4  = __attribute__((ext_vector_type(4))) float;
using bf16x8 = __attribute__((ext_vector_type(8))) __bf16;
using u16x4  = __attribute__((ext_vector_type(4))) unsigned short;

#define BK 64
#define REG_HALF   8192      // ushorts: 128 rows x 64 cols
#define A_OFS      0
#define B_OFS      16384
#define BUF_STRIDE 32768     // one buffer = A(32KB)+B(32KB) = 64 KB

#define BARRIER() asm volatile("s_barrier" ::: "memory")

__device__ __forceinline__ unsigned short f32_to_bf16_bits(float f) {
    unsigned int u = __builtin_bit_cast(unsigned int, f);
    u = (u + 0x7fffu + ((u >> 16) & 1u)) >> 16;
    return (unsigned short)u;
}

__device__ __forceinline__ void gload_lds16(const void* g, void* l) {
    __builtin_amdgcn_global_load_lds(
        (const __attribute__((address_space(1))) unsigned int*)g,
        (__attribute__((address_space(3))) unsigned int*)l,
        16, 0, 0);
}

// ---------------------------------------------------------------------------
// Fake-quant x (exact-f32 math, bf16 store) and W f32->bf16. Unchanged.
// ---------------------------------------------------------------------------
__global__ void quant_kernel(const float* __restrict__ x,
                             unsigned short* __restrict__ xq,
                             int total4) {
    int idx = blockIdx.x * 256 + threadIdx.x;
    if (idx >= total4) return;
    f32x4 v = *(const f32x4*)(x + (size_t)idx * 4);
    float am = fmaxf(fmaxf(fabsf(v[0]), fabsf(v[1])),
                     fmaxf(fabsf(v[2]), fabsf(v[3])));
    am = fmaxf(am, __shfl_xor(am, 1));
    am = fmaxf(am, __shfl_xor(am, 2));
    am = fmaxf(am, __shfl_xor(am, 4));
    am = fmaxf(am, __shfl_xor(am, 8));
    float delta = fmaxf(am / 127.0f, 1e-5f);
    u16x4 o;
#pragma unroll
    for (int i = 0; i < 4; ++i) {
        float q = rintf(v[i] / delta);
        q = fminf(fmaxf(q, -127.0f), 127.0f);
        o[i] = f32_to_bf16_bits(q * delta);
    }
    *(u16x4*)(xq + (size_t)idx * 4) = o;
}

__global__ void wconv_kernel(const float* __restrict__ W,
                             unsigned short* __restrict__ Wb,
                             int total4) {
    int idx = blockIdx.x * 256 + threadIdx.x;
    if (idx >= total4) return;
    f32x4 v = *(const f32x4*)(W + (size_t)idx * 4);
    u16x4 o;
#pragma unroll
    for (int i = 0; i < 4; ++i) o[i] = f32_to_bf16_bits(v[i]);
    *(u16x4*)(Wb + (size_t)idx * 4) = o;
}

// ---------------------------------------------------------------------------
// Staging: one half-region (128 LDS rows x 64 cols bf16 = 16 KB) per call,
// 2 x global_load_lds(16B) per thread. LDS dest is LINEAR (wave-uniform base
// + lane*16); the T2 swizzle and the region row-permutation are applied to
// the GLOBAL source address (rule #21: both-sides-or-neither).
// Row permutations (region-local row gr in [0,128), half h):
//   A: global tile row = (gr>>6)*128 + h*64 + (gr&63)
//      -> region h holds each wave-row-block's m-frags [h*4 .. h*4+4)
//   B: global tile row = (gr>>5)*64  + h*32 + (gr&31)
//      -> region h holds each wave-col-block's n-frags [h*2 .. h*2+2)
// ---------------------------------------------------------------------------
__device__ __forceinline__ void stage_A_half(
    const unsigned short* __restrict__ G,   // A + bm0*K + kt*BK
    int K, unsigned short* lds_region, int h, int tid)
{
#pragma unroll
    for (int it = 0; it < 2; ++it) {
        int g  = it * 512 + tid;
        int gr = g >> 3;
        int c  = ((g & 7) ^ (gr & 7)) << 3;
        int r  = ((gr >> 6) << 7) + h * 64 + (gr & 63);
        gload_lds16(G + (size_t)r * K + c, lds_region + g * 8);
    }
}

__device__ __forceinline__ void stage_B_half(
    const unsigned short* __restrict__ G,   // B + bn0*K + kt*BK
    int K, unsigned short* lds_region, int h, int tid)
{
#pragma unroll
    for (int it = 0; it < 2; ++it) {
        int g  = it * 512 + tid;
        int gr = g >> 3;
        int c  = ((g & 7) ^ (gr & 7)) << 3;
        int r  = ((gr >> 5) << 6) + h * 32 + (gr & 31);
        gload_lds16(G + (size_t)r * K + c, lds_region + g * 8);
    }
}

// ---------------------------------------------------------------------------
// 256x256 8-phase bf16 GEMM (B^T layout), m201-style schedule in plain HIP.
// Per K-tile: 4 phases, each {ds_read frags; stage 1 dead half-region;
// barrier; setprio(1); 16 MFMA; setprio(0); barrier}; counted vmcnt(4) at
// the tile boundary only. Stage stream for tile tau:
//   A-h0 @ (tau-2).p3, B-h0 @ (tau-2).p4, A-h1 @ (tau-1).p1, B-h1 @ (tau-1).p2
// Region deaths (phases read: A-h0 p1,p2; A-h1 p3,p4; B-h0 p1,p3; B-h1 p2,p4)
// make every in-buffer overwrite land strictly after its killing barrier.
// ---------------------------------------------------------------------------
__global__ __launch_bounds__(512, 2) void gemm_kernel(
    const unsigned short* __restrict__ A,   // [M][K] bf16 bits (quantized x)
    const unsigned short* __restrict__ B,   // [N][K] bf16 bits (W)
    const float* __restrict__ bias,         // [N]
    float* __restrict__ out,                // [M][N] f32
    int M, int N, int K)
{
    __shared__ unsigned short lds[2 * BUF_STRIDE];   // 128 KiB

    const int tid  = threadIdx.x;
    const int lane = tid & 63;
    const int wv   = tid >> 6;
    const int wm   = wv >> 2;        // 0..1  (128 rows each)
    const int wn   = wv & 3;         // 0..3  (64 cols each)
    const int lr   = lane & 15;
    const int lk   = lane >> 4;      // 0..3
    const int sx   = lr & 7;

    const int nbn = N / 256;
    const int nwg = gridDim.x;
    const int cpx = nwg >> 3;        // bijective XCD swizzle (nwg % 8 == 0)
    const int swz = (blockIdx.x & 7) * cpx + (blockIdx.x >> 3);
    const int bm0 = (swz / nbn) * 256;
    const int bn0 = (swz % nbn) * 256;

    const unsigned short* Ag = A + (size_t)bm0 * K;
    const unsigned short* Bg = B + (size_t)bn0 * K;
    const int NT = K / BK;

    f32x4 acc[8][4] = {};

    // Prologue: tile0 complete -> buf0 (8 loads); tile1 A-h0,B-h0 -> buf1 (4).
    stage_A_half(Ag,      K, lds + A_OFS,                         0, tid);
    stage_A_half(Ag,      K, lds + A_OFS + REG_HALF,              1, tid);
    stage_B_half(Bg,      K, lds + B_OFS,                         0, tid);
    stage_B_half(Bg,      K, lds + B_OFS + REG_HALF,              1, tid);
    stage_A_half(Ag + BK, K, lds + BUF_STRIDE + A_OFS,            0, tid);
    stage_B_half(Bg + BK, K, lds + BUF_STRIDE + B_OFS,            0, tid);
    asm volatile("s_waitcnt vmcnt(4)" ::: "memory");   // tile0 landed
    BARRIER();

#pragma unroll 2
    for (int t = 0; t < NT; ++t) {
        const int cb = t & 1;
        unsigned short* cbase = lds + cb * BUF_STRIDE;
        unsigned short* nbase = lds + (cb ^ 1) * BUF_STRIDE;

        bf16x8 af[4][2], bfr[2][2];

        // ---- phase 1: quad (m0-3, n0-1); stage A-h1(t+1) -> next buf ----
#pragma unroll
        for (int m = 0; m < 4; ++m)
#pragma unroll
            for (int kk = 0; kk < 2; ++kk)
                af[m][kk] = *(const bf16x8*)(cbase + A_OFS
                    + (wm * 64 + m * 16 + lr) * 64 + ((((kk << 2) + lk) ^ sx) << 3));
#pragma unroll
        for (int n = 0; n < 2; ++n)
#pragma unroll
            for (int kk = 0; kk < 2; ++kk)
                bfr[n][kk] = *(const bf16x8*)(cbase + B_OFS
                    + (wn * 32 + n * 16 + lr) * 64 + ((((kk << 2) + lk) ^ sx) << 3));
        if (t + 1 < NT)
            stage_A_half(Ag + (size_t)(t + 1) * BK, K, nbase + A_OFS + REG_HALF, 1, tid);
        BARRIER();
        __builtin_amdgcn_s_setprio(1);
#pragma unroll
        for (int m = 0; m < 4; ++m)
#pragma unroll
            for (int n = 0; n < 2; ++n)
#pragma unroll
                for (int kk = 0; kk < 2; ++kk)
                    acc[m][n] = __builtin_amdgcn_mfma_f32_16x16x32_bf16(
                        af[m][kk], bfr[n][kk], acc[m][n], 0, 0, 0);
        __builtin_amdgcn_s_setprio(0);
        BARRIER();

        // ---- phase 2: quad (m0-3, n2-3); stage B-h1(t+1) -> next buf ----
#pragma unroll
        for (int n = 0; n < 2; ++n)
#pragma unroll
            for (int kk = 0; kk < 2; ++kk)
                bfr[n][kk] = *(const bf16x8*)(cbase + B_OFS
                    + (128 + wn * 32 + n * 16 + lr) * 64 + ((((kk << 2) + lk) ^ sx) << 3));
        if (t + 1 < NT)
            stage_B_half(Bg + (size_t)(t + 1) * BK, K, nbase + B_OFS + REG_HALF, 1, tid);
        BARRIER();
        __builtin_amdgcn_s_setprio(1);
#pragma unroll
        for (int m = 0; m < 4; ++m)
#pragma unroll
            for (int n = 0; n < 2; ++n)
#pragma unroll
                for (int kk = 0; kk < 2; ++kk)
                    acc[m][2 + n] = __builtin_amdgcn_mfma_f32_16x16x32_bf16(
                        af[m][kk], bfr[n][kk], acc[m][2 + n], 0, 0, 0);
        __builtin_amdgcn_s_setprio(0);
        BARRIER();

        // ---- phase 3: quad (m4-7, n0-1); stage A-h0(t+2) -> THIS buf ----
        //      (A-h0 of tile t died at end of phase 2)
#pragma unroll
        for (int m = 0; m < 4; ++m)
#pragma unroll
            for (int kk = 0; kk < 2; ++kk)
                af[m][kk] = *(const bf16x8*)(cbase + A_OFS
                    + (128 + wm * 64 + m * 16 + lr) * 64 + ((((kk << 2) + lk) ^ sx) << 3));
#pragma unroll
        for (int n = 0; n < 2; ++n)
#pragma unroll
            for (int kk = 0; kk < 2; ++kk)
                bfr[n][kk] = *(const bf16x8*)(cbase + B_OFS
                    + (wn * 32 + n * 16 + lr) * 64 + ((((kk << 2) + lk) ^ sx) << 3));
        if (t + 2 < NT)
            stage_A_half(Ag + (size_t)(t + 2) * BK, K, cbase + A_OFS, 0, tid);
        BARRIER();
        __builtin_amdgcn_s_setprio(1);
#pragma unroll
        for (int m = 0; m < 4; ++m)
#pragma unroll
            for (int n = 0; n < 2; ++n)
#pragma unroll
                for (int kk = 0; kk < 2; ++kk)
                    acc[4 + m][n] = __builtin_amdgcn_mfma_f32_16x16x32_bf16(
                        af[m][kk], bfr[n][kk], acc[4 + m][n], 0, 0, 0);
        __builtin_amdgcn_s_setprio(0);
        BARRIER();

        // ---- phase 4: quad (m4-7, n2-3); stage B-h0(t+2) -> THIS buf ----
        //      (B-h0 of tile t died at end of phase 3)
#pragma unroll
        for (int n = 0; n < 2; ++n)
#pragma unroll
            for (int kk = 0; kk < 2; ++kk)
                bfr[n][kk] = *(const bf16x8*)(cbase + B_OFS
                    + (128 + wn * 32 + n * 16 + lr) * 64 + ((((kk << 2) + lk) ^ sx) << 3));
        if (t + 2 < NT)
            stage_B_half(Bg + (size_t)(t + 2) * BK, K, cbase + B_OFS, 0, tid);
        BARRIER();
        __builtin_amdgcn_s_setprio(1);
#pragma unroll
        for (int m = 0; m < 4; ++m)
#pragma unroll
            for (int n = 0; n < 2; ++n)
#pragma unroll
                for (int kk = 0; kk < 2; ++kk)
                    acc[4 + m][2 + n] = __builtin_amdgcn_mfma_f32_16x16x32_bf16(
                        af[m][kk], bfr[n][kk], acc[4 + m][2 + n], 0, 0, 0);
        __builtin_amdgcn_s_setprio(0);
        // ---- tile boundary: wait tile t+1 landed (keep t+2's 4 loads in
        //      flight), then rendezvous. Never vmcnt(0) until the tail. ----
        if (t + 2 < NT) asm volatile("s_waitcnt vmcnt(4)" ::: "memory");
        else            asm volatile("s_waitcnt vmcnt(0)" ::: "memory");
        BARRIER();
    }

    // Epilogue: C/D layout col = lane&15, row = (lane>>4)*4 + j  [m89]
    const int r0   = bm0 + wm * 128;
    const int c0   = bn0 + wn * 64;
    const int rsub = lk << 2;
#pragma unroll
    for (int nf = 0; nf < 4; ++nf) {
        int col = c0 + nf * 16 + lr;
        float bv = bias[col];
#pragma unroll
        for (int mf = 0; mf < 8; ++mf) {
            int row = r0 + mf * 16 + rsub;
#pragma unroll
            for (int j = 0; j < 4; ++j)
                out[(size_t)(row + j) * N + col] = acc[mf][nf][j] + bv;
        }
    }
}

extern "C" void kernel_launch(void* const* d_in, const int* in_sizes, int n_in,
                              void* d_out, int out_size, void* d_ws, size_t ws_size,
                              hipStream_t stream) {
    const float* x = (const float*)d_in[0];   // [M][K] f32
    const float* W = (const float*)d_in[1];   // [N][K] f32
    const float* b = (const float*)d_in[2];   // [N]   f32
    float* out = (float*)d_out;               // [M][N] f32

    const int N = in_sizes[2];                // 4096
    const int K = in_sizes[1] / N;            // 4096
    const int M = in_sizes[0] / K;            // 8192

    unsigned short* xq = (unsigned short*)d_ws;            // 64 MB
    unsigned short* Wb = xq + (size_t)M * K;               // 32 MB

    const int t4x = (int)(((long long)M * K) / 4);
    quant_kernel<<<(t4x + 255) / 256, 256, 0, stream>>>(x, xq, t4x);
    const int t4w = (int)(((long long)N * K) / 4);
    wconv_kernel<<<(t4w + 255) / 256, 256, 0, stream>>>(W, Wb, t4w);

    dim3 grid((M / 256) * (N / 256));         // 512 blocks
    gemm_kernel<<<grid, 512, 0, stream>>>(xq, Wb, b, out, M, N, K);
}

// Round 4
// 290.202 us; speedup vs baseline: 1.5335x; 1.0598x over previous
//
#include <hip/hip_runtime.h>

using f32x4  = __attribute__((ext_vector_type(4))) float;
using bf16x8 = __attribute__((ext_vector_type(8))) __bf16;
using u16x4  = __attribute__((ext_vector_type(4))) unsigned short;

#define BK 64
#define REG_HALF   8192      // ushorts: 128 rows x 64 cols
#define A_OFS      0
#define B_OFS      16384
#define BUF_STRIDE 32768     // one buffer = A(32KB)+B(32KB) = 64 KB

#define BARRIER() asm volatile("s_barrier" ::: "memory")

__device__ __forceinline__ unsigned short f32_to_bf16_bits(float f) {
    unsigned int u = __builtin_bit_cast(unsigned int, f);
    u = (u + 0x7fffu + ((u >> 16) & 1u)) >> 16;
    return (unsigned short)u;
}

__device__ __forceinline__ void gload_lds16(const void* g, void* l) {
    __builtin_amdgcn_global_load_lds(
        (const __attribute__((address_space(1))) unsigned int*)g,
        (__attribute__((address_space(3))) unsigned int*)l,
        16, 0, 0);
}

// ---------------------------------------------------------------------------
// Fake-quant x (exact-f32 math, bf16 store) and W f32->bf16. Unchanged.
// ---------------------------------------------------------------------------
__global__ void quant_kernel(const float* __restrict__ x,
                             unsigned short* __restrict__ xq,
                             int total4) {
    int idx = blockIdx.x * 256 + threadIdx.x;
    if (idx >= total4) return;
    f32x4 v = *(const f32x4*)(x + (size_t)idx * 4);
    float am = fmaxf(fmaxf(fabsf(v[0]), fabsf(v[1])),
                     fmaxf(fabsf(v[2]), fabsf(v[3])));
    am = fmaxf(am, __shfl_xor(am, 1));
    am = fmaxf(am, __shfl_xor(am, 2));
    am = fmaxf(am, __shfl_xor(am, 4));
    am = fmaxf(am, __shfl_xor(am, 8));
    float delta = fmaxf(am / 127.0f, 1e-5f);
    u16x4 o;
#pragma unroll
    for (int i = 0; i < 4; ++i) {
        float q = rintf(v[i] / delta);
        q = fminf(fmaxf(q, -127.0f), 127.0f);
        o[i] = f32_to_bf16_bits(q * delta);
    }
    *(u16x4*)(xq + (size_t)idx * 4) = o;
}

__global__ void wconv_kernel(const float* __restrict__ W,
                             unsigned short* __restrict__ Wb,
                             int total4) {
    int idx = blockIdx.x * 256 + threadIdx.x;
    if (idx >= total4) return;
    f32x4 v = *(const f32x4*)(W + (size_t)idx * 4);
    u16x4 o;
#pragma unroll
    for (int i = 0; i < 4; ++i) o[i] = f32_to_bf16_bits(v[i]);
    *(u16x4*)(Wb + (size_t)idx * 4) = o;
}

// ---------------------------------------------------------------------------
// Staging helpers: one half-region (16 KB) per call, 2 x gload_lds(16B)
// per thread. LDS dest LINEAR; T2 swizzle + region row-permutation applied
// to the GLOBAL source address (rule #21).
//   A: global tile row = (gr>>6)*128 + h*64 + (gr&63)   (h0: m-frags 0-3)
//   B: global tile row = (gr>>5)*64  + h*32 + (gr&31)   (h0: n-frags 0-1)
// ---------------------------------------------------------------------------
__device__ __forceinline__ void stage_A_half(
    const unsigned short* __restrict__ G, int K,
    unsigned short* lds_region, int h, int tid)
{
#pragma unroll
    for (int it = 0; it < 2; ++it) {
        int g  = it * 512 + tid;
        int gr = g >> 3;
        int c  = ((g & 7) ^ (gr & 7)) << 3;
        int r  = ((gr >> 6) << 7) + h * 64 + (gr & 63);
        gload_lds16(G + (size_t)r * K + c, lds_region + g * 8);
    }
}

__device__ __forceinline__ void stage_B_half(
    const unsigned short* __restrict__ G, int K,
    unsigned short* lds_region, int h, int tid)
{
#pragma unroll
    for (int it = 0; it < 2; ++it) {
        int g  = it * 512 + tid;
        int gr = g >> 3;
        int c  = ((g & 7) ^ (gr & 7)) << 3;
        int r  = ((gr >> 5) << 6) + h * 32 + (gr & 31);
        gload_lds16(G + (size_t)r * K + c, lds_region + g * 8);
    }
}

// ---------------------------------------------------------------------------
// 256x256 bf16 GEMM (B^T), pipelined-within-tile schedule:
// per K-tile: issue ALL 24 ds_read_b128 up front (afL,bfA,bfB,afH), stage
// 2 half-regions -> next buf, MFMA Q1 (compiler waits lgkm(12); reads 13-24
// deliver under the MFMA), mid-barrier, stage 2 half-regions -> this buf's
// dead h0 regions, MFMA Q2-Q4 back-to-back (lgkm(8)/lgkm(0) waits), counted
// vmcnt(4) + boundary barrier. 2 barriers/tile, vmcnt never 0 until tail.
// Region deaths: reads 1-12 (cbuf h0) done all-waves at mid-barrier -> h0
// overwrite safe; nbuf h1 overwrite safe at tile start (prev tile's lgkm(0)
// before its Q3 preceded its boundary barrier).
// ---------------------------------------------------------------------------
__global__ __launch_bounds__(512, 2) void gemm_kernel(
    const unsigned short* __restrict__ A,   // [M][K] bf16 bits (quantized x)
    const unsigned short* __restrict__ B,   // [N][K] bf16 bits (W)
    const float* __restrict__ bias,         // [N]
    float* __restrict__ out,                // [M][N] f32
    int M, int N, int K)
{
    __shared__ unsigned short lds[2 * BUF_STRIDE];   // 128 KiB

    const int tid  = threadIdx.x;
    const int lane = tid & 63;
    const int wv   = tid >> 6;
    const int wm   = wv >> 2;        // 0..1  (128 rows each)
    const int wn   = wv & 3;         // 0..3  (64 cols each)
    const int lr   = lane & 15;
    const int lk   = lane >> 4;      // 0..3
    const int sx   = lr & 7;

    const int nbn = N / 256;
    const int nwg = gridDim.x;
    const int cpx = nwg >> 3;        // bijective XCD swizzle (nwg % 8 == 0)
    const int swz = (blockIdx.x & 7) * cpx + (blockIdx.x >> 3);
    const int bm0 = (swz / nbn) * 256;
    const int bn0 = (swz % nbn) * 256;

    const unsigned short* Ag = A + (size_t)bm0 * K;
    const unsigned short* Bg = B + (size_t)bn0 * K;
    const int NT = K / BK;

    f32x4 acc[8][4] = {};

    // Prologue: tile0 complete -> buf0 (8 loads); tile1 h0 halves -> buf1 (4).
    stage_A_half(Ag,      K, lds + A_OFS,              0, tid);
    stage_A_half(Ag,      K, lds + A_OFS + REG_HALF,   1, tid);
    stage_B_half(Bg,      K, lds + B_OFS,              0, tid);
    stage_B_half(Bg,      K, lds + B_OFS + REG_HALF,   1, tid);
    stage_A_half(Ag + BK, K, lds + BUF_STRIDE + A_OFS, 0, tid);
    stage_B_half(Bg + BK, K, lds + BUF_STRIDE + B_OFS, 0, tid);
    asm volatile("s_waitcnt vmcnt(4)" ::: "memory");   // tile0 landed
    BARRIER();

#pragma unroll 2
    for (int t = 0; t < NT; ++t) {
        const int cb = t & 1;
        unsigned short* cbase = lds + cb * BUF_STRIDE;
        unsigned short* nbase = lds + (cb ^ 1) * BUF_STRIDE;

        // ---- issue ALL fragment reads for this tile (in-order: Q1 first) --
        bf16x8 afL[4][2], afH[4][2], bfA[2][2], bfB[2][2];
#pragma unroll
        for (int m = 0; m < 4; ++m)
#pragma unroll
            for (int kk = 0; kk < 2; ++kk)
                afL[m][kk] = *(const bf16x8*)(cbase + A_OFS
                    + (wm * 64 + m * 16 + lr) * 64 + ((((kk << 2) + lk) ^ sx) << 3));
#pragma unroll
        for (int n = 0; n < 2; ++n)
#pragma unroll
            for (int kk = 0; kk < 2; ++kk)
                bfA[n][kk] = *(const bf16x8*)(cbase + B_OFS
                    + (wn * 32 + n * 16 + lr) * 64 + ((((kk << 2) + lk) ^ sx) << 3));
#pragma unroll
        for (int n = 0; n < 2; ++n)
#pragma unroll
            for (int kk = 0; kk < 2; ++kk)
                bfB[n][kk] = *(const bf16x8*)(cbase + B_OFS
                    + (128 + wn * 32 + n * 16 + lr) * 64 + ((((kk << 2) + lk) ^ sx) << 3));
#pragma unroll
        for (int m = 0; m < 4; ++m)
#pragma unroll
            for (int kk = 0; kk < 2; ++kk)
                afH[m][kk] = *(const bf16x8*)(cbase + A_OFS
                    + (128 + wm * 64 + m * 16 + lr) * 64 + ((((kk << 2) + lk) ^ sx) << 3));

        // ---- stage t+1's h1 halves -> next buf (dead since prev tile) ----
        if (t + 1 < NT) {
            stage_A_half(Ag + (size_t)(t + 1) * BK, K, nbase + A_OFS + REG_HALF, 1, tid);
            stage_B_half(Bg + (size_t)(t + 1) * BK, K, nbase + B_OFS + REG_HALF, 1, tid);
        }

        // ---- Q1: (m0-3, n0-1) — compiler waits lgkm(12); 13-24 in flight --
        __builtin_amdgcn_s_setprio(1);
#pragma unroll
        for (int m = 0; m < 4; ++m)
#pragma unroll
            for (int n = 0; n < 2; ++n)
#pragma unroll
                for (int kk = 0; kk < 2; ++kk)
                    acc[m][n] = __builtin_amdgcn_mfma_f32_16x16x32_bf16(
                        afL[m][kk], bfA[n][kk], acc[m][n], 0, 0, 0);
        __builtin_amdgcn_s_setprio(0);
        BARRIER();   // all waves' reads 1-12 delivered -> cbuf h0 is dead

        // ---- stage t+2's h0 halves -> THIS buf's dead h0 regions ----
        if (t + 2 < NT) {
            stage_A_half(Ag + (size_t)(t + 2) * BK, K, cbase + A_OFS, 0, tid);
            stage_B_half(Bg + (size_t)(t + 2) * BK, K, cbase + B_OFS, 0, tid);
        }

        // ---- Q2-Q4 back-to-back (lgkm(8) / lgkm(0) auto-inserted) ----
        __builtin_amdgcn_s_setprio(1);
#pragma unroll
        for (int m = 0; m < 4; ++m)
#pragma unroll
            for (int n = 0; n < 2; ++n)
#pragma unroll
                for (int kk = 0; kk < 2; ++kk)
                    acc[m][2 + n] = __builtin_amdgcn_mfma_f32_16x16x32_bf16(
                        afL[m][kk], bfB[n][kk], acc[m][2 + n], 0, 0, 0);
#pragma unroll
        for (int m = 0; m < 4; ++m)
#pragma unroll
            for (int n = 0; n < 2; ++n)
#pragma unroll
                for (int kk = 0; kk < 2; ++kk)
                    acc[4 + m][n] = __builtin_amdgcn_mfma_f32_16x16x32_bf16(
                        afH[m][kk], bfA[n][kk], acc[4 + m][n], 0, 0, 0);
#pragma unroll
        for (int m = 0; m < 4; ++m)
#pragma unroll
            for (int n = 0; n < 2; ++n)
#pragma unroll
                for (int kk = 0; kk < 2; ++kk)
                    acc[4 + m][2 + n] = __builtin_amdgcn_mfma_f32_16x16x32_bf16(
                        afH[m][kk], bfB[n][kk], acc[4 + m][2 + n], 0, 0, 0);
        __builtin_amdgcn_s_setprio(0);

        // ---- boundary: tile t+1 must be fully landed; keep t+2's 4 loads
        //      in flight (vmcnt never 0 until the tail) ----
        if (t + 2 < NT) asm volatile("s_waitcnt vmcnt(4)" ::: "memory");
        else            asm volatile("s_waitcnt vmcnt(0)" ::: "memory");
        BARRIER();
    }

    // Epilogue: C/D layout col = lane&15, row = (lane>>4)*4 + j  [m89]
    const int r0   = bm0 + wm * 128;
    const int c0   = bn0 + wn * 64;
    const int rsub = lk << 2;
#pragma unroll
    for (int nf = 0; nf < 4; ++nf) {
        int col = c0 + nf * 16 + lr;
        float bv = bias[col];
#pragma unroll
        for (int mf = 0; mf < 8; ++mf) {
            int row = r0 + mf * 16 + rsub;
#pragma unroll
            for (int j = 0; j < 4; ++j)
                out[(size_t)(row + j) * N + col] = acc[mf][nf][j] + bv;
        }
    }
}

extern "C" void kernel_launch(void* const* d_in, const int* in_sizes, int n_in,
                              void* d_out, int out_size, void* d_ws, size_t ws_size,
                              hipStream_t stream) {
    const float* x = (const float*)d_in[0];   // [M][K] f32
    const float* W = (const float*)d_in[1];   // [N][K] f32
    const float* b = (const float*)d_in[2];   // [N]   f32
    float* out = (float*)d_out;               // [M][N] f32

    const int N = in_sizes[2];                // 4096
    const int K = in_sizes[1] / N;            // 4096
    const int M = in_sizes[0] / K;            // 8192

    unsigned short* xq = (unsigned short*)d_ws;            // 64 MB
    unsigned short* Wb = xq + (size_t)M * K;               // 32 MB

    const int t4x = (int)(((long long)M * K) / 4);
    quant_kernel<<<(t4x + 255) / 256, 256, 0, stream>>>(x, xq, t4x);
    const int t4w = (int)(((long long)N * K) / 4);
    wconv_kernel<<<(t4w + 255) / 256, 256, 0, stream>>>(W, Wb, t4w);

    dim3 grid((M / 256) * (N / 256));         // 512 blocks
    gemm_kernel<<<grid, 512, 0, stream>>>(xq, Wb, b, out, M, N, K);
}